// Round 2
// baseline (130.690 us; speedup 1.0000x reference)
//
#include <hip/hip_runtime.h>

#define NQ 9
#define NS 512            // 2^9 amplitudes
#define M2 1024           // [Re V; Im V] stacked rows
#define NSIMB 512         // sim blocks: 1 column each (128 threads = 2 waves)

#define COEF_ROT_BASE (72*32)                 // 72 ent steps x 32 floats
#define COEF_R3_BASE  (COEF_ROT_BASE + 27*8)  // + 27 rots x 8 floats
#define COEF_FLOATS   (COEF_R3_BASE + 3*128)  // + 3 merged 8x8 rot tables

typedef __attribute__((ext_vector_type(8))) short bf16x8;
typedef __attribute__((ext_vector_type(4))) float f32x4;

__device__ inline unsigned short f2bf(float f){
  unsigned int u = __float_as_uint(f);
  u += 0x7fffu + ((u >> 16) & 1u);   // round-to-nearest-even
  return (unsigned short)(u >> 16);
}

// =====================  2-wave-per-column statevector sim  =====================
// One column per 128-thread block. Amp i = (wvb<<8)|(r<<6)|lane : bits0-5 lane,
// bits6-7 register r (4 amps/thread), bit8 wave. Wire w <-> bit (8-w).
// Only ops touching bit 8 need an LDS exchange round (22 rounds, strict A/B
// ping-pong, one pair-local __syncthreads each). Rest is reg/DPP/swizzle.

template<int LM>
__device__ inline float lxor(float v){
  if constexpr (LM == 1)
    return __int_as_float(__builtin_amdgcn_mov_dpp(__float_as_int(v), 0xB1, 0xF, 0xF, true));
  else if constexpr (LM == 2)
    return __int_as_float(__builtin_amdgcn_mov_dpp(__float_as_int(v), 0x4E, 0xF, 0xF, true));
  else if constexpr (LM == 3)
    return __int_as_float(__builtin_amdgcn_mov_dpp(__float_as_int(v), 0x1B, 0xF, 0xF, true));
  else if constexpr (LM < 32)
    return __int_as_float(__builtin_amdgcn_ds_swizzle(__float_as_int(v), (LM<<10)|0x1F));
  else
    return __shfl_xor(v, LM);
}

template<int M>
__device__ inline float lx(float v){
  if constexpr ((M & 63) == 0) return v;
  else return lxor<(M & 63)>(v);
}

// partner value for xor-mask M: reg part from (own | partner-wave) regs, lane part via lxor
template<int M>
__device__ inline void getp(const float (&ox)[4], const float (&oy)[4],
                            const float2 (&pv)[4], int r, float& qx, float& qy){
  constexpr int MR = (M >> 6) & 3;
  float vx, vy;
  if constexpr ((M & 0x100) != 0){ vx = pv[r^MR].x; vy = pv[r^MR].y; }
  else                           { vx = ox[r^MR];   vy = oy[r^MR];   }
  qx = lx<M>(vx); qy = lx<M>(vy);
}

// cross-wave exchange: publish own 4 regs, read partner wave's 4 regs (same lane)
__device__ inline void xwave(const float (&ax)[4], const float (&ay)[4],
                             int wvb, int lane, float2* xb, float2 (&pv)[4]){
  #pragma unroll
  for (int r = 0; r < 4; ++r) xb[(wvb*4+r)*64 + lane] = make_float2(ax[r], ay[r]);
  __syncthreads();
  #pragma unroll
  for (int r = 0; r < 4; ++r) pv[r] = xb[((wvb^1)*4+r)*64 + lane];
}

// fused 4x4 ent step on bit-pair (CM, TM)
template<int CM,int TM>
__device__ inline void stepQ(float (&ax)[4], float (&ay)[4], int wvb, int lane,
                             float2* xb, const float* g){
  constexpr bool HX = ((CM | TM) & 0x100) != 0;
  float2 pv[4];
  if constexpr (HX) xwave(ax, ay, wvb, lane, xb, pv);
  float ox[4], oy[4];
  #pragma unroll
  for (int r = 0; r < 4; ++r){ ox[r] = ax[r]; oy[r] = ay[r]; }
  #pragma unroll
  for (int r = 0; r < 4; ++r){
    float tx,ty,cx,cy,bx,by;
    getp<TM>(ox, oy, pv, r, tx, ty);
    getp<CM>(ox, oy, pv, r, cx, cy);
    getp<(CM^TM)>(ox, oy, pv, r, bx, by);
    int i = (wvb << 8) | (r << 6) | lane;
    int p = ((i & CM) ? 2 : 0) | ((i & TM) ? 1 : 0);
    float4 hx = *(const float4*)(g + p*4);
    float4 hy = *(const float4*)(g + 16 + p*4);
    ax[r] = hx.x*ox[r]-hy.x*oy[r] + hx.y*tx-hy.y*ty + hx.z*cx-hy.z*cy + hx.w*bx-hy.w*by;
    ay[r] = hx.x*oy[r]+hy.x*ox[r] + hx.y*ty+hy.y*tx + hx.z*cy+hy.z*cx + hx.w*by+hy.w*bx;
  }
}

// ent block: I=0 exchanges on bufA, I=8 on bufB, I=1..7 purely in-wave
template<int I = 0>
__device__ inline void ent_blkQ(float (&ax)[4], float (&ay)[4], int wvb, int lane,
                                float2* ebA, float2* ebB, const float* S){
  if constexpr      (I == 0) stepQ<0x100,0x080>(ax, ay, wvb, lane, ebA, S);
  else if constexpr (I == 8) stepQ<0x001,0x100>(ax, ay, wvb, lane, ebB, S + 256);
  else                       stepQ<(0x100>>I),(0x080>>I)>(ax, ay, wvb, lane, ebA, S + I*32);
  if constexpr (I < 8) ent_blkQ<I+1>(ax, ay, wvb, lane, ebA, ebB, S);
}

// merged Rot(w0)xRot(w1)xRot(w2) on bits 8,7,6: one exchange round + 8 cmacs/amp
__device__ inline void rot3Q(float (&ax)[4], float (&ay)[4], int wvb, int lane,
                             float2* xb, const float* Mt){
  float2 pv[4];
  xwave(ax, ay, wvb, lane, xb, pv);
  bool w1 = (wvb != 0);
  float l0x[4],l0y[4],l1x[4],l1y[4];  // amps with wave-bit 0 / 1
  #pragma unroll
  for (int r = 0; r < 4; ++r){
    l0x[r] = w1 ? pv[r].x : ax[r];  l0y[r] = w1 ? pv[r].y : ay[r];
    l1x[r] = w1 ? ax[r]   : pv[r].x; l1y[r] = w1 ? ay[r]   : pv[r].y;
  }
  #pragma unroll
  for (int r = 0; r < 4; ++r){
    const float4* row = (const float4*)(Mt + ((wvb<<2)|r)*16);
    float4 m0 = row[0], m1 = row[1], m2 = row[2], m3 = row[3];
    float nx, ny;
    nx  = m0.x*l0x[0]-m0.y*l0y[0];  ny  = m0.x*l0y[0]+m0.y*l0x[0];
    nx += m0.z*l0x[1]-m0.w*l0y[1];  ny += m0.z*l0y[1]+m0.w*l0x[1];
    nx += m1.x*l0x[2]-m1.y*l0y[2];  ny += m1.x*l0y[2]+m1.y*l0x[2];
    nx += m1.z*l0x[3]-m1.w*l0y[3];  ny += m1.z*l0y[3]+m1.w*l0x[3];
    nx += m2.x*l1x[0]-m2.y*l1y[0];  ny += m2.x*l1y[0]+m2.y*l1x[0];
    nx += m2.z*l1x[1]-m2.w*l1y[1];  ny += m2.z*l1y[1]+m2.w*l1x[1];
    nx += m3.x*l1x[2]-m3.y*l1y[2];  ny += m3.x*l1y[2]+m3.y*l1x[2];
    nx += m3.z*l1x[3]-m3.w*l1y[3];  ny += m3.z*l1y[3]+m3.w*l1x[3];
    ax[r] = nx; ay[r] = ny;
  }
}

// Rot on a lane-bit wire
template<int LM>
__device__ inline void rotQ(float (&ax)[4], float (&ay)[4], int lane, const float* u){
  float4 uu = *(const float4*)(u + ((lane & LM) ? 4 : 0));
  #pragma unroll
  for (int r = 0; r < 4; ++r){
    float px = lxor<LM>(ax[r]), py = lxor<LM>(ay[r]);
    float nx = uu.x*ax[r]-uu.y*ay[r] + uu.z*px-uu.w*py;
    float ny = uu.x*ay[r]+uu.y*ax[r] + uu.z*py+uu.w*px;
    ax[r] = nx; ay[r] = ny;
  }
}

template<int I = 3>
__device__ inline void sel_rotsQ(float (&ax)[4], float (&ay)[4], int lane, const float* ub){
  rotQ<(1<<(8-I))>(ax, ay, lane, ub + I*8);
  if constexpr (I < 8) sel_rotsQ<I+1>(ax, ay, lane, ub);
}

// ---- CNOT primitives (new[x] = old[x ^ (control?targetbit:0)]) ----
template<int TR>  // control = wave bit, target = reg bit
__device__ inline void cn_wr(float (&ax)[4], float (&ay)[4], int wvb){
  if (wvb){
    #pragma unroll
    for (int r = 0; r < 4; ++r) if (!(r & TR)){
      float t = ax[r]; ax[r] = ax[r|TR]; ax[r|TR] = t;
      t = ay[r]; ay[r] = ay[r|TR]; ay[r|TR] = t;
    }
  }
}
template<int TL>  // control = wave bit, target = lane bit
__device__ inline void cn_wl(float (&ax)[4], float (&ay)[4], int wvb){
  if (wvb){
    #pragma unroll
    for (int r = 0; r < 4; ++r){ ax[r] = lxor<TL>(ax[r]); ay[r] = lxor<TL>(ay[r]); }
  }
}
template<int CR,int TR>  // reg control, reg target
__device__ inline void cn_rr(float (&ax)[4], float (&ay)[4]){
  #pragma unroll
  for (int r = 0; r < 4; ++r) if ((r & CR) && !(r & TR)){
    float t = ax[r]; ax[r] = ax[r|TR]; ax[r|TR] = t;
    t = ay[r]; ay[r] = ay[r|TR]; ay[r|TR] = t;
  }
}
template<int CR,int TL>  // reg control, lane target
__device__ inline void cn_rl(float (&ax)[4], float (&ay)[4]){
  #pragma unroll
  for (int r = 0; r < 4; ++r) if (r & CR){ ax[r] = lxor<TL>(ax[r]); ay[r] = lxor<TL>(ay[r]); }
}
template<int CL,int TR>  // lane control, reg target
__device__ inline void cn_lr(float (&ax)[4], float (&ay)[4], int lane){
  bool c = (lane & CL) != 0;
  #pragma unroll
  for (int r = 0; r < 4; ++r) if (!(r & TR)){
    int rp = r | TR;
    float t0x = ax[r], t0y = ay[r];
    ax[r]  = c ? ax[rp] : t0x;  ay[r]  = c ? ay[rp] : t0y;
    ax[rp] = c ? t0x : ax[rp];  ay[rp] = c ? t0y : ay[rp];
  }
}
template<int CL,int TL>  // lane control, lane target
__device__ inline void cn_ll(float (&ax)[4], float (&ay)[4], int lane){
  bool c = (lane & CL) != 0;
  #pragma unroll
  for (int r = 0; r < 4; ++r){
    float px = lxor<TL>(ax[r]), py = lxor<TL>(ay[r]);
    ax[r] = c ? px : ax[r];  ay[r] = c ? py : ay[r];
  }
}
template<int CL>  // lane control, target = wave bit (the only exchange in a ring)
__device__ inline void cn_lw(float (&ax)[4], float (&ay)[4], int wvb, int lane, float2* xb){
  float2 pv[4];
  xwave(ax, ay, wvb, lane, xb, pv);
  bool c = (lane & CL) != 0;
  #pragma unroll
  for (int r = 0; r < 4; ++r){ ax[r] = c ? pv[r].x : ax[r]; ay[r] = c ? pv[r].y : ay[r]; }
}

// CNOT rings (gate order i=0..8, wire w <-> bit 8-w), range compile-time
__device__ inline void ring1(float (&ax)[4], float (&ay)[4], int wvb, int lane, float2* xb){
  cn_wr<2>(ax,ay,wvb);        // 0->1 : bit 8 -> 7
  cn_rr<2,1>(ax,ay);          // 1->2 : 7 -> 6
  cn_rl<1,32>(ax,ay);         // 2->3 : 6 -> 5
  cn_ll<32,16>(ax,ay,lane);   // 3->4
  cn_ll<16,8>(ax,ay,lane);    // 4->5
  cn_ll<8,4>(ax,ay,lane);     // 5->6
  cn_ll<4,2>(ax,ay,lane);     // 6->7
  cn_ll<2,1>(ax,ay,lane);     // 7->8
  cn_lw<1>(ax,ay,wvb,lane,xb);// 8->0 : bit 0 -> 8
}
__device__ inline void ring2(float (&ax)[4], float (&ay)[4], int wvb, int lane, float2* xb){
  cn_wr<1>(ax,ay,wvb);        // 0->2 : 8 -> 6
  cn_rl<2,32>(ax,ay);         // 1->3 : 7 -> 5
  cn_rl<1,16>(ax,ay);         // 2->4 : 6 -> 4
  cn_ll<32,8>(ax,ay,lane);    // 3->5
  cn_ll<16,4>(ax,ay,lane);    // 4->6
  cn_ll<8,2>(ax,ay,lane);     // 5->7
  cn_ll<4,1>(ax,ay,lane);     // 6->8
  cn_lw<2>(ax,ay,wvb,lane,xb);// 7->0 : bit 1 -> 8
  cn_lr<1,2>(ax,ay,lane);     // 8->1 : bit 0 -> 7
}
__device__ inline void ring3(float (&ax)[4], float (&ay)[4], int wvb, int lane, float2* xb){
  cn_wl<32>(ax,ay,wvb);       // 0->3 : 8 -> 5
  cn_rl<2,16>(ax,ay);         // 1->4 : 7 -> 4
  cn_rl<1,8>(ax,ay);          // 2->5 : 6 -> 3
  cn_ll<32,4>(ax,ay,lane);    // 3->6
  cn_ll<16,2>(ax,ay,lane);    // 4->7
  cn_ll<8,1>(ax,ay,lane);     // 5->8
  cn_lw<4>(ax,ay,wvb,lane,xb);// 6->0 : bit 2 -> 8
  cn_lr<2,2>(ax,ay,lane);     // 7->1 : bit 1 -> 7
  cn_lr<1,1>(ax,ay,lane);     // 8->2 : bit 0 -> 6
}

// A2 layout (b128-friendly): ushort index = (c*1024 + row)*8 + d*2 + j,
// where column t = 8c + 2d + j; row = amp (Re) or 512+amp (Im).
// => 16 consecutive bytes at (c*1024+row)*16 hold k = 8c..8c+7 for that row.

// Combined kernel: blocks [0,NSIMB) simulate 1 V column each; blocks >= NSIMB run prep.
__global__ __launch_bounds__(128) void sim_prep(const float* __restrict__ params,
                                                const float* __restrict__ weights,
                                                const float* __restrict__ params2,
                                                const float* __restrict__ adds,
                                                unsigned short* __restrict__ A2,
                                                unsigned short* __restrict__ cT,
                                                float* __restrict__ out, int B){
  int tid = threadIdx.x;

  if (blockIdx.x >= NSIMB){
    // ---- prep path: build c (wave per sample) + zero the output accumulator ----
    int gid = (blockIdx.x - NSIMB) * 128 + tid;
    int b = gid >> 6;
    int lane = gid & 63;
    if (b < B){
      const float* ab = adds + b * NQ;
      float cw[NQ], sw[NQ];
      #pragma unroll
      for (int w = 0; w < NQ; ++w)
        __sincosf(0.5f * ab[w], &sw[w], &cw[w]);
      float p6 = 1.f;
      #pragma unroll
      for (int w = 0; w < 6; ++w)
        p6 *= ((lane >> (5 - w)) & 1) ? sw[w] : cw[w];
      union { unsigned short u[8]; uint4 v; } pk;
      #pragma unroll
      for (int j = 0; j < 8; ++j){
        float p = p6 * (((j>>2)&1) ? sw[6] : cw[6])
                     * (((j>>1)&1) ? sw[7] : cw[7])
                     * (( j    &1) ? sw[8] : cw[8]);
        pk.u[j] = f2bf(p);
      }
      *(uint4*)(cT + (size_t)b * NS + lane*8) = pk.v;
    }
    if (gid < B) out[gid] = 0.f;
    return;
  }

  // ---- sim path: one column, 2 waves, pair-local barriers ----
  __shared__ float2 ebufA[512];   // [wvb][r][lane], ping
  __shared__ float2 ebufB[512];   // pong
  __shared__ float scoef[COEF_FLOATS];

  // inline coefficient precompute into LDS
  if (tid < 72){
    int blk = tid / 9, I = tid % 9;
    const float* p = (blk < 3) ? params + blk*36 : params2 + (blk-3)*36;
    float s0,c0,s1,c1,s2,c2,s3,c3;
    __sincosf(0.5f*p[4*I+0], &s0, &c0);
    __sincosf(0.5f*p[4*I+1], &s1, &c1);
    __sincosf(0.5f*p[4*I+2], &s2, &c2);
    __sincosf(0.5f*p[4*I+3], &s3, &c3);
    float m[4][4] = {
      { c0*c1, -c0*s1, -s0*c1,  s0*s1},
      { c0*s1,  c0*c1, -s0*s1, -s0*c1},
      { s0*c1, -s0*s1,  c0*c1, -c0*s1},
      { s0*s1,  s0*c1,  c0*s1,  c0*c1}};
    float gx[4][4], gy[4][4];
    #pragma unroll
    for (int q = 0; q < 4; ++q){
      gx[0][q] = m[1][q];  gy[0][q] = 0.f;      // row swap from X(q_target)
      gx[1][q] = m[0][q];  gy[1][q] = 0.f;
      gx[2][q] =  c3*c2*m[2][q] - s3*s2*m[3][q];
      gy[2][q] =  c3*s2*m[2][q] - s3*c2*m[3][q];
      gx[3][q] =  s3*s2*m[2][q] + c3*c2*m[3][q];
      gy[3][q] = -(s3*c2*m[2][q] + c3*s2*m[3][q]);
    }
    float* dst = scoef + tid*32;
    #pragma unroll
    for (int pp = 0; pp < 4; ++pp)
      #pragma unroll
      for (int d = 0; d < 4; ++d){
        dst[pp*4+d]    = gx[pp][pp^d];   // Hx[p][d] = Gx[p][p^d]
        dst[16+pp*4+d] = gy[pp][pp^d];
      }
  } else if (tid < 99){
    int r = tid - 72;
    int l = r / 9, i = r % 9;
    const float* w = weights + l*27 + 3*i;
    float phi = w[0], th = w[1], om = w[2];
    float sT,cT,sA,cA,sB,cB;
    __sincosf(0.5f*th, &sT, &cT);
    __sincosf(0.5f*(phi+om), &sA, &cA);
    __sincosf(0.5f*(om-phi), &sB, &cB);
    float* dst = scoef + COEF_ROT_BASE + r*8;
    dst[0] =  cA*cT;  dst[1] = -sA*cT;   // side 0: u00 (diag), u01 (off)
    dst[2] = -cB*sT;  dst[3] =  sB*sT;
    dst[4] =  cA*cT;  dst[5] =  sA*cT;   // side 1: u11 (diag), u10 (off)
    dst[6] =  cB*sT;  dst[7] =  sB*sT;
  } else if (tid < 123){
    // merged Rot(w0) x Rot(w1) x Rot(w2) tables: 24 threads = (layer l, row p)
    int idx = tid - 99;
    int l = idx >> 3, p = idx & 7;
    float e0x[3], e0y[3], e1x[3], e1y[3];
    #pragma unroll
    for (int w = 0; w < 3; ++w){
      const float* wp = weights + l*27 + 3*w;
      float phi = wp[0], th = wp[1], om = wp[2];
      float sT,cT,sA,cA,sB,cB;
      __sincosf(0.5f*th, &sT, &cT);
      __sincosf(0.5f*(phi+om), &sA, &cA);
      __sincosf(0.5f*(om-phi), &sB, &cB);
      int pw = (p >> (2 - w)) & 1;
      if (pw == 0){ e0x[w] =  cA*cT; e0y[w] = -sA*cT; e1x[w] = -cB*sT; e1y[w] =  sB*sT; }
      else        { e0x[w] =  cB*sT; e0y[w] =  sB*sT; e1x[w] =  cA*cT; e1y[w] =  sA*cT; }
    }
    float* dst = scoef + COEF_R3_BASE + l*128 + p*16;
    #pragma unroll
    for (int q = 0; q < 8; ++q){
      float rx = 1.f, ry = 0.f;
      #pragma unroll
      for (int w = 0; w < 3; ++w){
        int qw = (q >> (2 - w)) & 1;
        float fx = qw ? e1x[w] : e0x[w];
        float fy = qw ? e1y[w] : e0y[w];
        float nx = rx*fx - ry*fy;
        float ny = rx*fy + ry*fx;
        rx = nx; ry = ny;
      }
      dst[q*2]   = rx;
      dst[q*2+1] = ry;
    }
  }
  __syncthreads();

  int wvb = tid >> 6, lane = tid & 63;
  int col = blockIdx.x;

  float ax[4], ay[4];
  int pc = __popc((unsigned)col) & 3;
  float prx = (pc==0) ? 1.f : (pc==2 ? -1.f : 0.f);
  float pry = (pc==3) ? 1.f : (pc==1 ? -1.f : 0.f);
  #pragma unroll
  for (int r = 0; r < 4; ++r){
    int i = (wvb<<8) | (r<<6) | lane;
    ax[r] = (i == col) ? prx : 0.f;
    ay[r] = (i == col) ? pry : 0.f;
  }

  #pragma unroll 1
  for (int blk = 0; blk < 3; ++blk)
    ent_blkQ<0>(ax, ay, wvb, lane, ebufA, ebufB, scoef + blk*288);

  rot3Q(ax, ay, wvb, lane, ebufA, scoef + COEF_R3_BASE + 0*128);
  sel_rotsQ<3>(ax, ay, lane, scoef + COEF_ROT_BASE + 0*72);
  ring1(ax, ay, wvb, lane, ebufB);
  rot3Q(ax, ay, wvb, lane, ebufA, scoef + COEF_R3_BASE + 1*128);
  sel_rotsQ<3>(ax, ay, lane, scoef + COEF_ROT_BASE + 1*72);
  ring2(ax, ay, wvb, lane, ebufB);
  rot3Q(ax, ay, wvb, lane, ebufA, scoef + COEF_R3_BASE + 2*128);
  sel_rotsQ<3>(ax, ay, lane, scoef + COEF_ROT_BASE + 2*72);
  ring3(ax, ay, wvb, lane, ebufB);

  #pragma unroll 1
  for (int blk = 3; blk < 8; ++blk)
    ent_blkQ<0>(ax, ay, wvb, lane, ebufA, ebufB, scoef + blk*288);

  // ---- direct A2 stores (no LDS round): this wave owns Re+Im of its amps ----
  int c = col >> 3, d = (col >> 1) & 3, j = col & 1;
  size_t base = (size_t)c * 1024;
  int sub = d*2 + j;
  #pragma unroll
  for (int r = 0; r < 4; ++r){
    int i = (wvb<<8) | (r<<6) | lane;
    A2[(base + i)*8 + sub]       = f2bf(ax[r]);   // Re row i
    A2[(base + 512 + i)*8 + sub] = f2bf(ay[r]);   // Im row 512+i
  }
}

// Phi2 = A2(1024x512) @ c(512xB); out[b] = sum_row sign(row) * Phi2[row][b]^2,
// sign(row) = -1 iff (row & 256). A2: 16B at (c*1024+row)*16 = k=8c..8c+7 of row.
__global__ __launch_bounds__(256) void gemm_out(const unsigned short* __restrict__ A2,
                                                const unsigned short* __restrict__ cT,
                                                float* __restrict__ out){
  int bx = blockIdx.x;            // N tile (128 cols of b)
  int by = blockIdx.y;            // M tile (128 rows), 8 tiles
  int tid = threadIdx.x;
  int wave = tid >> 6, lane = tid & 63;
  int wy = wave >> 1, wx = wave & 1;
  int lane15 = lane & 15, quad = lane >> 4;
  int rowBase = by*128 + wy*64;
  int colBase = bx*128 + wx*64;
  const bf16x8* Ap8 = (const bf16x8*)A2;   // 16B units: (c*1024 + row)
  const short* Bp = (const short*)cT;      // [col][k]

  f32x4 acc[4][4];
  #pragma unroll
  for (int i = 0; i < 4; ++i)
    #pragma unroll
    for (int j = 0; j < 4; ++j)
      acc[i][j] = (f32x4){0.f, 0.f, 0.f, 0.f};

  #pragma unroll 4
  for (int k0 = 0; k0 < NS; k0 += 32){
    bf16x8 a[4], b[4];
    int c = (k0 >> 3) + quad;
    #pragma unroll
    for (int mi = 0; mi < 4; ++mi)
      a[mi] = Ap8[(size_t)c*1024 + rowBase + mi*16 + lane15];
    #pragma unroll
    for (int ni = 0; ni < 4; ++ni)
      b[ni] = *(const bf16x8*)(Bp + (size_t)(colBase + ni*16 + lane15)*NS + k0 + quad*8);
    #pragma unroll
    for (int mi = 0; mi < 4; ++mi)
      #pragma unroll
      for (int ni = 0; ni < 4; ++ni)
        acc[mi][ni] = __builtin_amdgcn_mfma_f32_16x16x32_bf16(a[mi], b[ni], acc[mi][ni], 0, 0, 0);
  }

  float sign = (by & 2) ? -1.f : 1.f;
  #pragma unroll
  for (int ni = 0; ni < 4; ++ni){
    float cs = 0.f;
    #pragma unroll
    for (int mi = 0; mi < 4; ++mi)
      #pragma unroll
      for (int r = 0; r < 4; ++r)
        cs += acc[mi][ni][r] * acc[mi][ni][r];
    cs += __shfl_xor(cs, 16);
    cs += __shfl_xor(cs, 32);
    if (quad == 0)
      atomicAdd(out + colBase + ni*16 + lane15, sign * cs);
  }
}

extern "C" void kernel_launch(void* const* d_in, const int* in_sizes, int n_in,
                              void* d_out, int out_size, void* d_ws, size_t ws_size,
                              hipStream_t stream) {
  const float* adds    = (const float*)d_in[0];
  const float* params  = (const float*)d_in[1];
  const float* weights = (const float*)d_in[2];
  const float* params2 = (const float*)d_in[3];
  float* out = (float*)d_out;
  int B = in_sizes[0] / NQ;   // 8192

  unsigned short* A2 = (unsigned short*)d_ws;        // 1024*512 bf16 = 1 MB (c-blocked)
  unsigned short* cT = A2 + (size_t)M2 * NS;         // B*512 bf16 = 8 MB

  int prepBlocks = (B * 64 + 127) / 128;             // 4096
  hipLaunchKernelGGL(sim_prep, dim3(NSIMB + prepBlocks), dim3(128), 0, stream,
                     params, weights, params2, adds, A2, cT, out, B);
  hipLaunchKernelGGL(gemm_out, dim3(B / 128, 8), dim3(256), 0, stream, A2, cT, out);
}

// Round 3
// 106.144 us; speedup vs baseline: 1.2312x; 1.2312x over previous
//
#include <hip/hip_runtime.h>

#define NQ 9
#define NS 512            // 2^9 amplitudes
#define M2 1024           // [Re V; Im V] stacked rows
#define NSIMB 512         // sim blocks: 1 column each (256 threads = 4 waves)

#define COEF_ROT_BASE (72*32)                 // 72 ent steps x 32 floats
#define COEF_R3_BASE  (COEF_ROT_BASE + 27*8)  // + 27 rots x 8 floats
#define COEF_FLOATS   (COEF_R3_BASE + 3*128)  // + 3 merged 8x8 rot tables

typedef __attribute__((ext_vector_type(8))) short bf16x8;
typedef __attribute__((ext_vector_type(4))) float f32x4;

__device__ inline unsigned short f2bf(float f){
  unsigned int u = __float_as_uint(f);
  u += 0x7fffu + ((u >> 16) & 1u);   // round-to-nearest-even
  return (unsigned short)(u >> 16);
}

// =====================  4-wave-per-column statevector sim (r=2)  =====================
// One column per 256-thread block. Amp i = (w<<7)|(r<<6)|lane : bits0-5 lane,
// bit6 register r (2 amps/thread), bits7-8 wave id w. Wire wr <-> bit (8-wr).
// Ops touching bits 7/8 use an LDS exchange round (31 rounds total, strict A/B
// ping-pong, one __syncthreads each). Rest is reg/DPP/swizzle local.

template<int LM>
__device__ inline float lxor(float v){
  if constexpr (LM == 1)
    return __int_as_float(__builtin_amdgcn_mov_dpp(__float_as_int(v), 0xB1, 0xF, 0xF, true));
  else if constexpr (LM == 2)
    return __int_as_float(__builtin_amdgcn_mov_dpp(__float_as_int(v), 0x4E, 0xF, 0xF, true));
  else if constexpr (LM == 3)
    return __int_as_float(__builtin_amdgcn_mov_dpp(__float_as_int(v), 0x1B, 0xF, 0xF, true));
  else if constexpr (LM < 32)
    return __int_as_float(__builtin_amdgcn_ds_swizzle(__float_as_int(v), (LM<<10)|0x1F));
  else
    return __shfl_xor(v, LM);
}

template<int M>
__device__ inline float lx(float v){
  if constexpr ((M & 63) == 0) return v;
  else return lxor<(M & 63)>(v);
}

// local partner for xor-mask M (reg bit 6 + lane bits only)
template<int M>
__device__ inline void getp2(const float (&ox)[2], const float (&oy)[2],
                             int r, float& qx, float& qy){
  constexpr int MR = (M >> 6) & 1;
  qx = lx<M>(ox[r ^ MR]);
  qy = lx<M>(oy[r ^ MR]);
}

// fused 4x4 ent step on bit-pair (CM, TM); LDS exchange iff a wave bit involved
template<int CM,int TM>
__device__ inline void stepQ2(float (&ax)[2], float (&ay)[2], int w, int lane,
                              float2* xb, const float* g){
  constexpr bool HX = ((CM | TM) & 0x180) != 0;
  float ox[2] = {ax[0], ax[1]}, oy[2] = {ay[0], ay[1]};
  float tx[2],ty[2],cx[2],cy[2],bx[2],by[2];
  if constexpr (HX){
    #pragma unroll
    for (int r = 0; r < 2; ++r) xb[(w<<7)|(r<<6)|lane] = make_float2(ox[r], oy[r]);
    __syncthreads();
    #pragma unroll
    for (int r = 0; r < 2; ++r){
      int i = (w<<7)|(r<<6)|lane;
      float2 tv = xb[i^TM], cv = xb[i^CM], bv = xb[i^(CM^TM)];
      tx[r]=tv.x; ty[r]=tv.y; cx[r]=cv.x; cy[r]=cv.y; bx[r]=bv.x; by[r]=bv.y;
    }
  } else {
    #pragma unroll
    for (int r = 0; r < 2; ++r){
      getp2<TM>(ox, oy, r, tx[r], ty[r]);
      getp2<CM>(ox, oy, r, cx[r], cy[r]);
      getp2<(CM^TM)>(ox, oy, r, bx[r], by[r]);
    }
  }
  #pragma unroll
  for (int r = 0; r < 2; ++r){
    int i = (w<<7)|(r<<6)|lane;
    int p = ((i & CM) ? 2 : 0) | ((i & TM) ? 1 : 0);
    float4 hx = *(const float4*)(g + p*4);
    float4 hy = *(const float4*)(g + 16 + p*4);
    ax[r] = hx.x*ox[r]-hy.x*oy[r] + hx.y*tx[r]-hy.y*ty[r]
          + hx.z*cx[r]-hy.z*cy[r] + hx.w*bx[r]-hy.w*by[r];
    ay[r] = hx.x*oy[r]+hy.x*ox[r] + hx.y*ty[r]+hy.y*tx[r]
          + hx.z*cy[r]+hy.z*cx[r] + hx.w*by[r]+hy.w*bx[r];
  }
}

// ent block; exchange rounds: I0 -> bX, I1 -> bY, I8 -> bX (3 rounds, parity flips)
__device__ inline void ent_blk2(float (&ax)[2], float (&ay)[2], int w, int lane,
                                float2* bX, float2* bY, const float* S){
  stepQ2<0x100,0x080>(ax, ay, w, lane, bX, S);
  stepQ2<0x080,0x040>(ax, ay, w, lane, bY, S + 32);
  stepQ2<0x040,0x020>(ax, ay, w, lane, bX, S + 64);    // local (xb unused)
  stepQ2<0x020,0x010>(ax, ay, w, lane, bX, S + 96);
  stepQ2<0x010,0x008>(ax, ay, w, lane, bX, S + 128);
  stepQ2<0x008,0x004>(ax, ay, w, lane, bX, S + 160);
  stepQ2<0x004,0x002>(ax, ay, w, lane, bX, S + 192);
  stepQ2<0x002,0x001>(ax, ay, w, lane, bX, S + 224);
  stepQ2<0x001,0x100>(ax, ay, w, lane, bX, S + 256);
}

// merged Rot(w0)xRot(w1)xRot(w2) on bits 8,7,6: one exchange round, 8 cmacs/amp
__device__ inline void rot3Q2(float (&ax)[2], float (&ay)[2], int w, int lane,
                              float2* xb, const float* Mt){
  #pragma unroll
  for (int r = 0; r < 2; ++r) xb[(w<<7)|(r<<6)|lane] = make_float2(ax[r], ay[r]);
  __syncthreads();
  #pragma unroll
  for (int r = 0; r < 2; ++r){
    const float* M = Mt + ((w<<1)|r)*16;
    float nx = 0.f, ny = 0.f;
    #pragma unroll
    for (int q = 0; q < 8; ++q){
      float2 v = xb[(q<<6)|lane];
      float mx = M[q*2], my = M[q*2+1];
      nx += mx*v.x - my*v.y;
      ny += mx*v.y + my*v.x;
    }
    ax[r] = nx; ay[r] = ny;
  }
}

// Rot on a lane-bit wire
template<int LM>
__device__ inline void rotQ2(float (&ax)[2], float (&ay)[2], int lane, const float* u){
  float4 uu = *(const float4*)(u + ((lane & LM) ? 4 : 0));
  #pragma unroll
  for (int r = 0; r < 2; ++r){
    float px = lxor<LM>(ax[r]), py = lxor<LM>(ay[r]);
    float nx = uu.x*ax[r]-uu.y*ay[r] + uu.z*px-uu.w*py;
    float ny = uu.x*ay[r]+uu.y*ax[r] + uu.z*py+uu.w*px;
    ax[r] = nx; ay[r] = ny;
  }
}

template<int I = 3>
__device__ inline void sel_rots2(float (&ax)[2], float (&ay)[2], int lane, const float* ub){
  rotQ2<(1<<(8-I))>(ax, ay, lane, ub + I*8);
  if constexpr (I < 8) sel_rots2<I+1>(ax, ay, lane, ub);
}

// ---- CNOT primitives ----
__device__ inline void swap2(float& a, float& b){ float t=a; a=b; b=t; }

template<int CL,int TL>  // lane control, lane target
__device__ inline void cn_ll2(float (&ax)[2], float (&ay)[2], int lane){
  bool c = (lane & CL) != 0;
  #pragma unroll
  for (int r = 0; r < 2; ++r){
    float px = lxor<TL>(ax[r]), py = lxor<TL>(ay[r]);
    ax[r] = c ? px : ax[r];  ay[r] = c ? py : ay[r];
  }
}

// generic exchange permutation round: amp i gets old[i ^ ((i>>C1&1)<<T1) ^ ((i>>C2&1)<<T2)]
template<int C1,int T1,int C2,int T2>
__device__ inline void cn_perm(float (&ax)[2], float (&ay)[2], int w, int lane, float2* xb){
  #pragma unroll
  for (int r = 0; r < 2; ++r) xb[(w<<7)|(r<<6)|lane] = make_float2(ax[r], ay[r]);
  __syncthreads();
  #pragma unroll
  for (int r = 0; r < 2; ++r){
    int i = (w<<7)|(r<<6)|lane;
    int j = i ^ (((i>>C1)&1)<<T1);
    if constexpr (C2 >= 0) j ^= ((i>>C2)&1)<<T2;
    float2 v = xb[j];
    ax[r] = v.x; ay[r] = v.y;
  }
}

// CNOT rings (gate order i=0..8, wire wr <-> bit 8-wr)
__device__ inline void ring1_2(float (&ax)[2], float (&ay)[2], int w, int lane,
                               float2* xA, float2* xB){
  cn_perm<8,7,-1,0>(ax, ay, w, lane, xA);                   // (8->7)
  if (w & 1){ swap2(ax[0],ax[1]); swap2(ay[0],ay[1]); }     // (7->6)
  ax[1]=lxor<32>(ax[1]); ay[1]=lxor<32>(ay[1]);             // (6->5)
  cn_ll2<32,16>(ax,ay,lane);                                // (5->4)
  cn_ll2<16,8>(ax,ay,lane);
  cn_ll2<8,4>(ax,ay,lane);
  cn_ll2<4,2>(ax,ay,lane);
  cn_ll2<2,1>(ax,ay,lane);                                  // (1->0)
  cn_perm<0,8,-1,0>(ax, ay, w, lane, xB);                   // (0->8)
}
__device__ inline void ring2_2(float (&ax)[2], float (&ay)[2], int w, int lane, float2* xB){
  if (w & 2){ swap2(ax[0],ax[1]); swap2(ay[0],ay[1]); }     // (8->6)
  if (w & 1){                                               // (7->5)
    #pragma unroll
    for (int r=0;r<2;++r){ ax[r]=lxor<32>(ax[r]); ay[r]=lxor<32>(ay[r]); }
  }
  ax[1]=lxor<16>(ax[1]); ay[1]=lxor<16>(ay[1]);             // (6->4)
  cn_ll2<32,8>(ax,ay,lane);                                 // (5->3)
  cn_ll2<16,4>(ax,ay,lane);
  cn_ll2<8,2>(ax,ay,lane);
  cn_ll2<4,1>(ax,ay,lane);                                  // (2->0)
  cn_perm<1,8,0,7>(ax, ay, w, lane, xB);                    // (1->8),(0->7) merged
}
__device__ inline void ring3_2(float (&ax)[2], float (&ay)[2], int w, int lane, float2* xB){
  if (w & 2){                                               // (8->5)
    #pragma unroll
    for (int r=0;r<2;++r){ ax[r]=lxor<32>(ax[r]); ay[r]=lxor<32>(ay[r]); }
  }
  if (w & 1){                                               // (7->4)
    #pragma unroll
    for (int r=0;r<2;++r){ ax[r]=lxor<16>(ax[r]); ay[r]=lxor<16>(ay[r]); }
  }
  ax[1]=lxor<8>(ax[1]); ay[1]=lxor<8>(ay[1]);               // (6->3)
  cn_ll2<32,4>(ax,ay,lane);                                 // (5->2)
  cn_ll2<16,2>(ax,ay,lane);
  cn_ll2<8,1>(ax,ay,lane);                                  // (3->0)
  cn_perm<2,8,1,7>(ax, ay, w, lane, xB);                    // (2->8),(1->7) merged
  bool c = (lane & 1) != 0;                                 // (0->6): lane ctrl -> reg
  float t0x = ax[0], t0y = ay[0];
  ax[0] = c ? ax[1] : ax[0];  ay[0] = c ? ay[1] : ay[0];
  ax[1] = c ? t0x   : ax[1];  ay[1] = c ? t0y   : ay[1];
}

// A2 layout (b128-friendly): ushort index = (c*1024 + row)*8 + sub,
// where column t = 8c + sub; row = amp (Re) or 512+amp (Im).
// => 16 consecutive bytes at (c*1024+row)*16 hold k = 8c..8c+7 for that row.

// Combined kernel: blocks [0,NSIMB) simulate 1 V column each; blocks >= NSIMB run prep.
__global__ __launch_bounds__(256) void sim_prep(const float* __restrict__ params,
                                                const float* __restrict__ weights,
                                                const float* __restrict__ params2,
                                                const float* __restrict__ adds,
                                                unsigned short* __restrict__ A2,
                                                unsigned short* __restrict__ cT,
                                                float* __restrict__ out, int B){
  int tid = threadIdx.x;

  if (blockIdx.x >= NSIMB){
    // ---- prep path: build c (wave per sample) + zero the output accumulator ----
    int gid = (blockIdx.x - NSIMB) * 256 + tid;
    int b = gid >> 6;
    int lane = gid & 63;
    if (b < B){
      const float* ab = adds + b * NQ;
      float cw[NQ], sw[NQ];
      #pragma unroll
      for (int w = 0; w < NQ; ++w)
        __sincosf(0.5f * ab[w], &sw[w], &cw[w]);
      float p6 = 1.f;
      #pragma unroll
      for (int w = 0; w < 6; ++w)
        p6 *= ((lane >> (5 - w)) & 1) ? sw[w] : cw[w];
      union { unsigned short u[8]; uint4 v; } pk;
      #pragma unroll
      for (int j = 0; j < 8; ++j){
        float p = p6 * (((j>>2)&1) ? sw[6] : cw[6])
                     * (((j>>1)&1) ? sw[7] : cw[7])
                     * (( j    &1) ? sw[8] : cw[8]);
        pk.u[j] = f2bf(p);
      }
      *(uint4*)(cT + (size_t)b * NS + lane*8) = pk.v;
    }
    if (gid < B) out[gid] = 0.f;
    return;
  }

  // ---- sim path: one column, 4 waves, r=2 amps/thread ----
  __shared__ float2 ebufA[512];   // amp-indexed exchange buffer, ping
  __shared__ float2 ebufB[512];   // pong
  __shared__ float scoef[COEF_FLOATS];

  // inline coefficient precompute into LDS
  if (tid < 72){
    int blk = tid / 9, I = tid % 9;
    const float* p = (blk < 3) ? params + blk*36 : params2 + (blk-3)*36;
    float s0,c0,s1,c1,s2,c2,s3,c3;
    __sincosf(0.5f*p[4*I+0], &s0, &c0);
    __sincosf(0.5f*p[4*I+1], &s1, &c1);
    __sincosf(0.5f*p[4*I+2], &s2, &c2);
    __sincosf(0.5f*p[4*I+3], &s3, &c3);
    float m[4][4] = {
      { c0*c1, -c0*s1, -s0*c1,  s0*s1},
      { c0*s1,  c0*c1, -s0*s1, -s0*c1},
      { s0*c1, -s0*s1,  c0*c1, -c0*s1},
      { s0*s1,  s0*c1,  c0*s1,  c0*c1}};
    float gx[4][4], gy[4][4];
    #pragma unroll
    for (int q = 0; q < 4; ++q){
      gx[0][q] = m[1][q];  gy[0][q] = 0.f;      // row swap from X(q_target)
      gx[1][q] = m[0][q];  gy[1][q] = 0.f;
      gx[2][q] =  c3*c2*m[2][q] - s3*s2*m[3][q];
      gy[2][q] =  c3*s2*m[2][q] - s3*c2*m[3][q];
      gx[3][q] =  s3*s2*m[2][q] + c3*c2*m[3][q];
      gy[3][q] = -(s3*c2*m[2][q] + c3*s2*m[3][q]);
    }
    float* dst = scoef + tid*32;
    #pragma unroll
    for (int pp = 0; pp < 4; ++pp)
      #pragma unroll
      for (int d = 0; d < 4; ++d){
        dst[pp*4+d]    = gx[pp][pp^d];   // Hx[p][d] = Gx[p][p^d]
        dst[16+pp*4+d] = gy[pp][pp^d];
      }
  } else if (tid < 99){
    int r = tid - 72;
    int l = r / 9, i = r % 9;
    const float* w = weights + l*27 + 3*i;
    float phi = w[0], th = w[1], om = w[2];
    float sT,cT,sA,cA,sB,cB;
    __sincosf(0.5f*th, &sT, &cT);
    __sincosf(0.5f*(phi+om), &sA, &cA);
    __sincosf(0.5f*(om-phi), &sB, &cB);
    float* dst = scoef + COEF_ROT_BASE + r*8;
    dst[0] =  cA*cT;  dst[1] = -sA*cT;   // side 0: u00 (diag), u01 (off)
    dst[2] = -cB*sT;  dst[3] =  sB*sT;
    dst[4] =  cA*cT;  dst[5] =  sA*cT;   // side 1: u11 (diag), u10 (off)
    dst[6] =  cB*sT;  dst[7] =  sB*sT;
  } else if (tid < 123){
    // merged Rot(w0) x Rot(w1) x Rot(w2) tables: 24 threads = (layer l, row p)
    int idx = tid - 99;
    int l = idx >> 3, p = idx & 7;
    float e0x[3], e0y[3], e1x[3], e1y[3];
    #pragma unroll
    for (int w = 0; w < 3; ++w){
      const float* wp = weights + l*27 + 3*w;
      float phi = wp[0], th = wp[1], om = wp[2];
      float sT,cT,sA,cA,sB,cB;
      __sincosf(0.5f*th, &sT, &cT);
      __sincosf(0.5f*(phi+om), &sA, &cA);
      __sincosf(0.5f*(om-phi), &sB, &cB);
      int pw = (p >> (2 - w)) & 1;
      if (pw == 0){ e0x[w] =  cA*cT; e0y[w] = -sA*cT; e1x[w] = -cB*sT; e1y[w] =  sB*sT; }
      else        { e0x[w] =  cB*sT; e0y[w] =  sB*sT; e1x[w] =  cA*cT; e1y[w] =  sA*cT; }
    }
    float* dst = scoef + COEF_R3_BASE + l*128 + p*16;
    #pragma unroll
    for (int q = 0; q < 8; ++q){
      float rx = 1.f, ry = 0.f;
      #pragma unroll
      for (int w = 0; w < 3; ++w){
        int qw = (q >> (2 - w)) & 1;
        float fx = qw ? e1x[w] : e0x[w];
        float fy = qw ? e1y[w] : e0y[w];
        float nx = rx*fx - ry*fy;
        float ny = rx*fy + ry*fx;
        rx = nx; ry = ny;
      }
      dst[q*2]   = rx;
      dst[q*2+1] = ry;
    }
  }
  __syncthreads();

  int w = tid >> 6, lane = tid & 63;
  int col = blockIdx.x;

  float ax[2], ay[2];
  int pc = __popc((unsigned)col) & 3;
  float prx = (pc==0) ? 1.f : (pc==2 ? -1.f : 0.f);
  float pry = (pc==3) ? 1.f : (pc==1 ? -1.f : 0.f);
  #pragma unroll
  for (int r = 0; r < 2; ++r){
    int i = (w<<7) | (r<<6) | lane;
    ax[r] = (i == col) ? prx : 0.f;
    ay[r] = (i == col) ? pry : 0.f;
  }

  // 31 exchange rounds, strict A/B alternation (see per-call buffer args)
  ent_blk2(ax, ay, w, lane, ebufA, ebufB, scoef + 0*288);   // A,B,A
  ent_blk2(ax, ay, w, lane, ebufB, ebufA, scoef + 1*288);   // B,A,B
  ent_blk2(ax, ay, w, lane, ebufA, ebufB, scoef + 2*288);   // A,B,A

  rot3Q2(ax, ay, w, lane, ebufB, scoef + COEF_R3_BASE + 0*128);   // B
  sel_rots2<3>(ax, ay, lane, scoef + COEF_ROT_BASE + 0*72);
  ring1_2(ax, ay, w, lane, ebufA, ebufB);                          // A,B

  rot3Q2(ax, ay, w, lane, ebufA, scoef + COEF_R3_BASE + 1*128);   // A
  sel_rots2<3>(ax, ay, lane, scoef + COEF_ROT_BASE + 1*72);
  ring2_2(ax, ay, w, lane, ebufB);                                 // B

  rot3Q2(ax, ay, w, lane, ebufA, scoef + COEF_R3_BASE + 2*128);   // A
  sel_rots2<3>(ax, ay, lane, scoef + COEF_ROT_BASE + 2*72);
  ring3_2(ax, ay, w, lane, ebufB);                                 // B

  ent_blk2(ax, ay, w, lane, ebufA, ebufB, scoef + 3*288);   // A,B,A
  ent_blk2(ax, ay, w, lane, ebufB, ebufA, scoef + 4*288);   // B,A,B
  ent_blk2(ax, ay, w, lane, ebufA, ebufB, scoef + 5*288);   // A,B,A
  ent_blk2(ax, ay, w, lane, ebufB, ebufA, scoef + 6*288);   // B,A,B
  ent_blk2(ax, ay, w, lane, ebufA, ebufB, scoef + 7*288);   // A,B,A

  // ---- direct A2 stores: this thread owns Re+Im of its 2 amps ----
  int c = col >> 3, sub = col & 7;
  size_t base = (size_t)c * 1024;
  #pragma unroll
  for (int r = 0; r < 2; ++r){
    int i = (w<<7) | (r<<6) | lane;
    A2[(base + i)*8 + sub]       = f2bf(ax[r]);   // Re row i
    A2[(base + 512 + i)*8 + sub] = f2bf(ay[r]);   // Im row 512+i
  }
}

// Phi2 = A2(1024x512) @ c(512xB); out[b] = sum_row sign(row) * Phi2[row][b]^2,
// sign(row) = -1 iff (row & 256). A2: 16B at (c*1024+row)*16 = k=8c..8c+7 of row.
__global__ __launch_bounds__(256) void gemm_out(const unsigned short* __restrict__ A2,
                                                const unsigned short* __restrict__ cT,
                                                float* __restrict__ out){
  int bx = blockIdx.x;            // N tile (128 cols of b)
  int by = blockIdx.y;            // M tile (128 rows), 8 tiles
  int tid = threadIdx.x;
  int wave = tid >> 6, lane = tid & 63;
  int wy = wave >> 1, wx = wave & 1;
  int lane15 = lane & 15, quad = lane >> 4;
  int rowBase = by*128 + wy*64;
  int colBase = bx*128 + wx*64;
  const bf16x8* Ap8 = (const bf16x8*)A2;   // 16B units: (c*1024 + row)
  const short* Bp = (const short*)cT;      // [col][k]

  f32x4 acc[4][4];
  #pragma unroll
  for (int i = 0; i < 4; ++i)
    #pragma unroll
    for (int j = 0; j < 4; ++j)
      acc[i][j] = (f32x4){0.f, 0.f, 0.f, 0.f};

  #pragma unroll 4
  for (int k0 = 0; k0 < NS; k0 += 32){
    bf16x8 a[4], b[4];
    int c = (k0 >> 3) + quad;
    #pragma unroll
    for (int mi = 0; mi < 4; ++mi)
      a[mi] = Ap8[(size_t)c*1024 + rowBase + mi*16 + lane15];
    #pragma unroll
    for (int ni = 0; ni < 4; ++ni)
      b[ni] = *(const bf16x8*)(Bp + (size_t)(colBase + ni*16 + lane15)*NS + k0 + quad*8);
    #pragma unroll
    for (int mi = 0; mi < 4; ++mi)
      #pragma unroll
      for (int ni = 0; ni < 4; ++ni)
        acc[mi][ni] = __builtin_amdgcn_mfma_f32_16x16x32_bf16(a[mi], b[ni], acc[mi][ni], 0, 0, 0);
  }

  float sign = (by & 2) ? -1.f : 1.f;
  #pragma unroll
  for (int ni = 0; ni < 4; ++ni){
    float cs = 0.f;
    #pragma unroll
    for (int mi = 0; mi < 4; ++mi)
      #pragma unroll
      for (int r = 0; r < 4; ++r)
        cs += acc[mi][ni][r] * acc[mi][ni][r];
    cs += __shfl_xor(cs, 16);
    cs += __shfl_xor(cs, 32);
    if (quad == 0)
      atomicAdd(out + colBase + ni*16 + lane15, sign * cs);
  }
}

extern "C" void kernel_launch(void* const* d_in, const int* in_sizes, int n_in,
                              void* d_out, int out_size, void* d_ws, size_t ws_size,
                              hipStream_t stream) {
  const float* adds    = (const float*)d_in[0];
  const float* params  = (const float*)d_in[1];
  const float* weights = (const float*)d_in[2];
  const float* params2 = (const float*)d_in[3];
  float* out = (float*)d_out;
  int B = in_sizes[0] / NQ;   // 8192

  unsigned short* A2 = (unsigned short*)d_ws;        // 1024*512 bf16 = 1 MB (c-blocked)
  unsigned short* cT = A2 + (size_t)M2 * NS;         // B*512 bf16 = 8 MB

  int prepBlocks = (B * 64 + 255) / 256;             // 2048
  hipLaunchKernelGGL(sim_prep, dim3(NSIMB + prepBlocks), dim3(256), 0, stream,
                     params, weights, params2, adds, A2, cT, out, B);
  hipLaunchKernelGGL(gemm_out, dim3(B / 128, 8), dim3(256), 0, stream, A2, cT, out);
}